// Round 4
// baseline (362.967 us; speedup 1.0000x reference)
//
#include <hip/hip_runtime.h>
#include <math.h>

// Problem constants
#define B_  4
#define L_  8192
#define D_  512

// MFMA GEMM tiling
#define BM   128
#define NCT  4                 // col tiles of 128
#define NRT  (L_ / BM)         // 64
#define NSTEP 16               // K = 512 / 32

// Scan chunking
#define CHUNK 64
#define NCHUNK (L_ / CHUNK)    // 128

#define MAXFIX 16380
#define FIX_TAU 1.5e-3f
#define FSLICE 8               // column slices in fixup (512/64)

typedef short bf16x8 __attribute__((ext_vector_type(8)));
typedef float f32x4 __attribute__((ext_vector_type(4)));
typedef unsigned short u16;
typedef u16 ushort8 __attribute__((ext_vector_type(8)));
typedef unsigned int u32;

__device__ __forceinline__ u16 f2bf_rne(float f) {
    unsigned u = __float_as_uint(f);
    unsigned r = (u + 0x7FFFu + ((u >> 16) & 1u)) >> 16;
    return (u16)r;
}

__device__ __forceinline__ ushort8 cvt8(float4 a, float4 b) {
    ushort8 r;
    r[0] = f2bf_rne(a.x); r[1] = f2bf_rne(a.y);
    r[2] = f2bf_rne(a.z); r[3] = f2bf_rne(a.w);
    r[4] = f2bf_rne(b.x); r[5] = f2bf_rne(b.y);
    r[6] = f2bf_rne(b.z); r[7] = f2bf_rne(b.w);
    return r;
}

__device__ __forceinline__ ushort8 ldcvt(const float* p) {
    float4 a = *(const float4*)p;
    float4 b = *(const float4*)(p + 4);
    return cvt8(a, b);
}

// ---------------------------------------------------------------------------
// Weight conversion: fp32 -> bf16 (hi only)
// ---------------------------------------------------------------------------
__global__ __launch_bounds__(256) void conv_w(
    const float* __restrict__ wq, const float* __restrict__ wk,
    u16* __restrict__ qh, u16* __restrict__ kh)
{
    int i = blockIdx.x * 256 + threadIdx.x;
    if (i >= D_ * D_) return;
    qh[i] = f2bf_rne(wq[i]);
    kh[i] = f2bf_rne(wk[i]);
}

__global__ void zero_fix(int* c) { if (threadIdx.x == 0 && blockIdx.x == 0) *c = 0; }

// ---------------------------------------------------------------------------
// Shared-A bf16 MFMA kernel (unchanged from round 3 — verified).
// part layout: [NCT][B][L][3]
// ---------------------------------------------------------------------------
__global__ __launch_bounds__(256, 2) void qk_mfma(
    const float* __restrict__ h,
    const u16* __restrict__ wqh, const u16* __restrict__ wkh,
    float* __restrict__ part)
{
    const int ct = blockIdx.x, rt = blockIdx.y, b = blockIdx.z;
    const int t = threadIdx.x, wid = t >> 6, lane = t & 63;
    const int l15 = lane & 15, l4 = lane >> 4;

    __shared__ __align__(16) u16 ah[144 * 32];   // rows 0..128 data; 129..143 zero
    __shared__ float red[4][BM][3];

    if (t < 240) ((u32*)ah)[2064 + t] = 0;       // zero rows 129..143

    const int r0 = rt * BM;
    const float* hb = h + (size_t)b * L_ * D_;

    const float* sp0 = hb + (size_t)(r0 + (t >> 2)) * D_ + (t & 3) * 8;
    const float* sp1 = hb + (size_t)(r0 + 64 + (t >> 2)) * D_ + (t & 3) * 8;
    int r128 = r0 + BM; if (r128 > L_ - 1) r128 = L_ - 1;
    const float* sp2 = hb + (size_t)r128 * D_ + (t & 3) * 8;   // t<4

    const int colb = ct * 128 + wid * 32;
    const u16* bq0 = wqh + (size_t)(colb + l15) * D_ + l4 * 8;
    const u16* bq1 = bq0 + (size_t)16 * D_;
    const u16* bk0 = wkh + (size_t)(colb + l15) * D_ + l4 * 8;
    const u16* bk1 = bk0 + (size_t)16 * D_;

    f32x4 accq[8][2], acck[8][2], ackl[2];
    const f32x4 zero = {0.f, 0.f, 0.f, 0.f};
#pragma unroll
    for (int rf = 0; rf < 8; ++rf) {
        accq[rf][0] = zero; accq[rf][1] = zero;
        acck[rf][0] = zero; acck[rf][1] = zero;
    }
    ackl[0] = zero; ackl[1] = zero;

    ushort8 c0 = ldcvt(sp0);
    ushort8 c1 = ldcvt(sp1);
    ushort8 c2 = {0,0,0,0,0,0,0,0};
    if (t < 4) c2 = ldcvt(sp2);

    for (int s = 0; s < NSTEP; ++s) {
        const int so = s * 32;
        __syncthreads();
        *(ushort8*)(&ah[t * 8]) = c0;
        *(ushort8*)(&ah[(t + 256) * 8]) = c1;
        if (t < 4) *(ushort8*)(&ah[(512 + t) * 8]) = c2;
        __syncthreads();

        bf16x8 fbq0 = *(const bf16x8*)(bq0 + so);
        bf16x8 fbq1 = *(const bf16x8*)(bq1 + so);
        bf16x8 fbk0 = *(const bf16x8*)(bk0 + so);
        bf16x8 fbk1 = *(const bf16x8*)(bk1 + so);

        const int sn = (s + 1 < NSTEP) ? (s + 1) * 32 : s * 32;
        c0 = ldcvt(sp0 + sn);
        c1 = ldcvt(sp1 + sn);
        if (t < 4) c2 = ldcvt(sp2 + sn);

#pragma unroll
        for (int rf = 0; rf < 8; ++rf) {
            bf16x8 a = *(const bf16x8*)(&ah[(rf * 16 + l15) * 32 + l4 * 8]);
            accq[rf][0] = __builtin_amdgcn_mfma_f32_16x16x32_bf16(a, fbq0, accq[rf][0], 0, 0, 0);
            accq[rf][1] = __builtin_amdgcn_mfma_f32_16x16x32_bf16(a, fbq1, accq[rf][1], 0, 0, 0);
            acck[rf][0] = __builtin_amdgcn_mfma_f32_16x16x32_bf16(a, fbk0, acck[rf][0], 0, 0, 0);
            acck[rf][1] = __builtin_amdgcn_mfma_f32_16x16x32_bf16(a, fbk1, acck[rf][1], 0, 0, 0);
        }
        bf16x8 al = *(const bf16x8*)(&ah[(128 + l15) * 32 + l4 * 8]);
        ackl[0] = __builtin_amdgcn_mfma_f32_16x16x32_bf16(al, fbk0, ackl[0], 0, 0, 0);
        ackl[1] = __builtin_amdgcn_mfma_f32_16x16x32_bf16(al, fbk1, ackl[1], 0, 0, 0);
    }

    // epilogue: per-row partials. C/D layout: col=lane&15, row=(lane>>4)*4+reg.
#pragma unroll
    for (int rf = 0; rf < 8; ++rf) {
#pragma unroll
        for (int reg = 0; reg < 4; ++reg) {
            float pq = 0.f, pk = 0.f, pd = 0.f;
#pragma unroll
            for (int cf = 0; cf < 2; ++cf) {
                float q  = accq[rf][cf][reg];
                float kv = acck[rf][cf][reg];
                pq += q * q;
                pk += kv * kv;
                float ksh;
                if (reg < 3) {
                    ksh = acck[rf][cf][reg + 1];
                } else {
                    float up = __shfl(acck[rf][cf][0], (lane + 16) & 63);
                    float nx0 = (rf < 7) ? acck[rf + 1][cf][0] : ackl[cf][0];
                    float nx = __shfl(nx0, l15);
                    ksh = (l4 == 3) ? nx : up;
                }
                pd += q * ksh;
            }
#pragma unroll
            for (int off = 1; off < 16; off <<= 1) {
                pq += __shfl_xor(pq, off);
                pk += __shfl_xor(pk, off);
                pd += __shfl_xor(pd, off);
            }
            if (l15 == 0) {
                int row = rf * 16 + l4 * 4 + reg;
                red[wid][row][0] = pq;
                red[wid][row][1] = pk;
                red[wid][row][2] = pd;
            }
        }
    }
    __syncthreads();
    if (t < BM) {
        float pq = red[0][t][0] + red[1][t][0] + red[2][t][0] + red[3][t][0];
        float pk = red[0][t][1] + red[1][t][1] + red[2][t][1] + red[3][t][1];
        float pd = red[0][t][2] + red[1][t][2] + red[2][t][2] + red[3][t][2];
        size_t o = (((size_t)ct * B_ + b) * L_ + (r0 + t)) * 3;
        part[o + 0] = pq; part[o + 1] = pk; part[o + 2] = pd;
    }
}

// ---------------------------------------------------------------------------
// reduce partials -> p (nk read shifted by one row); flag borderline rows
// ---------------------------------------------------------------------------
__global__ __launch_bounds__(256) void cos_reduce(
    const float* __restrict__ part, float* __restrict__ p,
    int* __restrict__ fix_cnt, int* __restrict__ fix_list)
{
    int idx = blockIdx.x * 256 + threadIdx.x;
    if (idx >= B_ * L_) return;
    int b = idx / L_;
    int tp = idx % L_;
    if (tp == 0) { p[idx] = 1.0f; return; }
    int l = tp - 1;
    float nq = 0.f, nk = 0.f, dt = 0.f;
#pragma unroll
    for (int ct = 0; ct < NCT; ++ct) {
        size_t o = (((size_t)ct * B_ + b) * L_ + l) * 3;
        nq += part[o + 0];
        dt += part[o + 2];
        nk += part[o + 4];        // part[...][l+1][1]
    }
    float qn = sqrtf(nq); if (qn < 1e-12f) qn = 1e-12f;
    float kn = sqrtf(nk); if (kn < 1e-12f) kn = 1e-12f;
    float cs = dt / (qn * kn);
    float pr = 0.5f * (1.0f - cs);
    pr = fminf(fmaxf(pr, 0.0f), 1.0f);
    p[idx] = pr;
    if (fabsf(cs) < FIX_TAU) {
        int slot = atomicAdd(fix_cnt, 1);
        if (slot < MAXFIX) fix_list[slot] = idx;
    }
}

// ---------------------------------------------------------------------------
// fp32 fixup, wave-parallel: item = (tile of 8 rows) x (64-col slice).
// lane = r*8 + ks : row r (lane>>3), k-slice ks (lane&7) of 64 floats.
// h slices live in registers; weight reads coalesced (f4, lanes span k).
// Partials go to private slots (deterministic, no atomics):
//   part_fix[slot s][slice cs][3]
// ---------------------------------------------------------------------------
__global__ __launch_bounds__(64) void fixup_main(
    const float* __restrict__ h, const float* __restrict__ wq,
    const float* __restrict__ wk, const int* __restrict__ fix_cnt,
    const int* __restrict__ fix_list, float* __restrict__ part_fix)
{
    const int lane = threadIdx.x;
    const int r  = lane >> 3;
    const int ks = lane & 7;
    int n = *fix_cnt; if (n > MAXFIX) n = MAXFIX;
    const int ntiles = (n + 7) / 8;
    const int nitems = ntiles * FSLICE;

    for (int item = blockIdx.x; item < nitems; item += gridDim.x) {
        const int tile = item >> 3;
        const int cs   = item & 7;
        const int s    = tile * 8 + r;
        const bool valid = (s < n);
        const int idx = fix_list[valid ? s : 0];
        const int bb = idx / L_, tp = idx % L_, l = tp - 1;
        const float* hq = h + ((size_t)bb * L_ + l) * D_ + ks * 64;
        const float* hk = hq + D_;
        float hqr[64], hkr[64];
#pragma unroll
        for (int j = 0; j < 16; ++j) {
            ((float4*)hqr)[j] = ((const float4*)hq)[j];
            ((float4*)hkr)[j] = ((const float4*)hk)[j];
        }
        float nqa = 0.f, nka = 0.f, dta = 0.f;
        const int c0 = cs * 64;
        for (int cc = 0; cc < 64; ++cc) {
            const int c = c0 + cc;
            const float4* wq4 = (const float4*)(wq + (size_t)c * D_ + ks * 64);
            const float4* wk4 = (const float4*)(wk + (size_t)c * D_ + ks * 64);
            float qp = 0.f, kp = 0.f;
#pragma unroll
            for (int j = 0; j < 16; ++j) {
                float4 wv = wq4[j];
                qp += wv.x * hqr[4*j]   + wv.y * hqr[4*j+1]
                    + wv.z * hqr[4*j+2] + wv.w * hqr[4*j+3];
                float4 xv = wk4[j];
                kp += xv.x * hkr[4*j]   + xv.y * hkr[4*j+1]
                    + xv.z * hkr[4*j+2] + xv.w * hkr[4*j+3];
            }
            qp += __shfl_xor(qp, 1); qp += __shfl_xor(qp, 2); qp += __shfl_xor(qp, 4);
            kp += __shfl_xor(kp, 1); kp += __shfl_xor(kp, 2); kp += __shfl_xor(kp, 4);
            nqa += qp * qp; nka += kp * kp; dta += qp * kp;
        }
        if (ks == 0 && valid) {
            float* pp = part_fix + ((size_t)s * FSLICE + cs) * 3;
            pp[0] = nqa; pp[1] = nka; pp[2] = dta;
        }
    }
}

__global__ __launch_bounds__(256) void fixup_final(
    const int* __restrict__ fix_cnt, const int* __restrict__ fix_list,
    const float* __restrict__ part_fix, float* __restrict__ p)
{
    int n = *fix_cnt; if (n > MAXFIX) n = MAXFIX;
    for (int s = blockIdx.x * 256 + threadIdx.x; s < n; s += gridDim.x * 256) {
        float nq = 0.f, nk = 0.f, dt = 0.f;
#pragma unroll
        for (int sl = 0; sl < FSLICE; ++sl) {
            const float* pp = part_fix + ((size_t)s * FSLICE + sl) * 3;
            nq += pp[0]; nk += pp[1]; dt += pp[2];
        }
        float qn = sqrtf(nq); if (qn < 1e-12f) qn = 1e-12f;
        float kn = sqrtf(nk); if (kn < 1e-12f) kn = 1e-12f;
        float cs = dt / (qn * kn);
        float pr = 0.5f * (1.0f - cs);
        pr = fminf(fmaxf(pr, 0.0f), 1.0f);
        p[fix_list[s]] = pr;
    }
}

// ---------------------------------------------------------------------------
// EMA scan, float2 per thread, branchless (unchanged from round 3)
// ---------------------------------------------------------------------------
__global__ __launch_bounds__(256) void scan_a(
    const float* __restrict__ h, const float* __restrict__ p,
    float* __restrict__ Bc, float* __restrict__ Ac)
{
    const int t = threadIdx.x;
    const int c = blockIdx.x, b = blockIdx.y;
    const int l0 = c * CHUNK;
    const float* pb = p + (size_t)b * L_ + l0;
    const float2* hb = (const float2*)(h + ((size_t)b * L_ + l0) * D_) + t;

    float2 st = {0.f, 0.f};
    float ap = 1.f;
#pragma unroll 4
    for (int i = 0; i < CHUNK; ++i) {
        float pr = pb[i];
        float2 hv = hb[(size_t)i * 256];
        bool sel = pr > 0.5f;
        float a = sel ? 1.f - pr : 1.f;
        float g = sel ? pr : 0.f;
        st.x = a * st.x + g * hv.x;
        st.y = a * st.y + g * hv.y;
        ap *= a;
    }
    ((float2*)Bc)[((size_t)b * NCHUNK + c) * 256 + t] = st;
    if (t == 0) Ac[b * NCHUNK + c] = ap;
}

__global__ __launch_bounds__(256) void scan_b(
    const float* __restrict__ Ac, const float* __restrict__ Bc,
    const float* __restrict__ det, float* __restrict__ carry)
{
    const int t = threadIdx.x;
    const int b = blockIdx.x;
    float2 st = ((const float2*)det)[(size_t)b * 256 + t];
    for (int c = 0; c < NCHUNK; ++c) {
        ((float2*)carry)[((size_t)b * NCHUNK + c) * 256 + t] = st;
        float a = Ac[b * NCHUNK + c];
        float2 bc = ((const float2*)Bc)[((size_t)b * NCHUNK + c) * 256 + t];
        st.x = a * st.x + bc.x;
        st.y = a * st.y + bc.y;
    }
}

__global__ __launch_bounds__(256) void scan_c(
    const float* __restrict__ h, const float* __restrict__ p,
    const float* __restrict__ res, const float* __restrict__ carry,
    float* __restrict__ out)
{
    const int t = threadIdx.x;
    const int c = blockIdx.x, b = blockIdx.y;
    const int l0 = c * CHUNK;
    const float* pb = p + (size_t)b * L_ + l0;
    const size_t base = ((size_t)b * L_ + l0) * 256 + t;   // float2 units
    const float2* hb = (const float2*)h + base;
    const float2* rb = (const float2*)res + base;
    float2* ob = (float2*)out + base;

    float2 st = ((const float2*)carry)[((size_t)b * NCHUNK + c) * 256 + t];
#pragma unroll 4
    for (int i = 0; i < CHUNK; ++i) {
        float pr = pb[i];
        float2 hv = hb[(size_t)i * 256];
        float2 rv = rb[(size_t)i * 256];
        bool sel = pr > 0.5f;
        float a = sel ? 1.f - pr : 1.f;
        float g = sel ? pr : 0.f;
        st.x = a * st.x + g * hv.x;
        st.y = a * st.y + g * hv.y;
        float2 ov; ov.x = rv.x + st.x; ov.y = rv.y + st.y;
        ob[(size_t)i * 256] = ov;
    }
}

// ---------------------------------------------------------------------------
extern "C" void kernel_launch(void* const* d_in, const int* in_sizes, int n_in,
                              void* d_out, int out_size, void* d_ws, size_t ws_size,
                              hipStream_t stream)
{
    const float* h   = (const float*)d_in[0];
    const float* res = (const float*)d_in[1];
    const float* wq  = (const float*)d_in[2];
    const float* wk  = (const float*)d_in[3];
    const float* det = (const float*)d_in[4];
    float* out = (float*)d_out;

    // ws layout (floats)
    float* ws = (float*)d_ws;
    float* part  = ws;                                     // NCT*B*L*3 = 393216
    float* p     = part + (size_t)NCT * B_ * L_ * 3;       // 32768
    float* Ac    = p + (size_t)B_ * L_;                    // 512
    float* Bc    = Ac + (size_t)B_ * NCHUNK;               // 262144
    float* carry = Bc + (size_t)B_ * NCHUNK * D_;          // 262144
    int*  fix_cnt  = (int*)(carry + (size_t)B_ * NCHUNK * D_);
    int*  fix_list = fix_cnt + 4;                          // MAXFIX ints
    u16* wqh = (u16*)(fix_list + MAXFIX);                  // D*D u16
    u16* wkh = wqh + (size_t)D_ * D_;
    float* part_fix = (float*)(wkh + (size_t)D_ * D_);     // MAXFIX*FSLICE*3

    conv_w<<<(D_ * D_ + 255) / 256, 256, 0, stream>>>(wq, wk, wqh, wkh);
    zero_fix<<<1, 64, 0, stream>>>(fix_cnt);
    qk_mfma<<<dim3(NCT, NRT, B_), 256, 0, stream>>>(h, wqh, wkh, part);
    cos_reduce<<<(B_ * L_ + 255) / 256, 256, 0, stream>>>(part, p, fix_cnt, fix_list);
    fixup_main<<<1024, 64, 0, stream>>>(h, wq, wk, fix_cnt, fix_list, part_fix);
    fixup_final<<<64, 256, 0, stream>>>(fix_cnt, fix_list, part_fix, p);
    scan_a<<<dim3(NCHUNK, B_), 256, 0, stream>>>(h, p, Bc, Ac);
    scan_b<<<B_, 256, 0, stream>>>(Ac, Bc, det, carry);
    scan_c<<<dim3(NCHUNK, B_), 256, 0, stream>>>(h, p, res, carry, out);
}

// Round 5
// 310.424 us; speedup vs baseline: 1.1693x; 1.1693x over previous
//
#include <hip/hip_runtime.h>
#include <math.h>

// Problem constants
#define B_  4
#define L_  8192
#define D_  512

// MFMA GEMM tiling
#define BM   128
#define NCT  4                 // col tiles of 128
#define NRT  (L_ / BM)         // 64
#define NSTEP 16               // K = 512 / 32

// Scan chunking
#define CHUNK 64
#define NCHUNK (L_ / CHUNK)    // 128

#define MAXFIX 16380
#define FIX_TAU 1.5e-3f
#define FTILE 8                // borderline rows per fixup block

typedef short bf16x8 __attribute__((ext_vector_type(8)));
typedef float f32x4 __attribute__((ext_vector_type(4)));
typedef unsigned short u16;
typedef u16 ushort8 __attribute__((ext_vector_type(8)));
typedef unsigned int u32;

__device__ __forceinline__ u16 f2bf_rne(float f) {
    unsigned u = __float_as_uint(f);
    unsigned r = (u + 0x7FFFu + ((u >> 16) & 1u)) >> 16;
    return (u16)r;
}

__device__ __forceinline__ ushort8 cvt8(float4 a, float4 b) {
    ushort8 r;
    r[0] = f2bf_rne(a.x); r[1] = f2bf_rne(a.y);
    r[2] = f2bf_rne(a.z); r[3] = f2bf_rne(a.w);
    r[4] = f2bf_rne(b.x); r[5] = f2bf_rne(b.y);
    r[6] = f2bf_rne(b.z); r[7] = f2bf_rne(b.w);
    return r;
}

__device__ __forceinline__ ushort8 ldcvt(const float* p) {
    float4 a = *(const float4*)p;
    float4 b = *(const float4*)(p + 4);
    return cvt8(a, b);
}

// ---------------------------------------------------------------------------
// Weight conversion: fp32 -> bf16 (hi only)
// ---------------------------------------------------------------------------
__global__ __launch_bounds__(256) void conv_w(
    const float* __restrict__ wq, const float* __restrict__ wk,
    u16* __restrict__ qh, u16* __restrict__ kh)
{
    int i = blockIdx.x * 256 + threadIdx.x;
    if (i >= D_ * D_) return;
    qh[i] = f2bf_rne(wq[i]);
    kh[i] = f2bf_rne(wk[i]);
}

// ---------------------------------------------------------------------------
// Blocked-transpose fp32 weights for the fixup:
//   wt[(k>>2)*2048 + c*4 + (k&3)] = w[c][k]
// so a float4 load at (kq*512 + c)*4 yields w[c][4kq .. 4kq+3].
// ---------------------------------------------------------------------------
__global__ __launch_bounds__(256) void transp_w(
    const float* __restrict__ wq, const float* __restrict__ wk,
    float* __restrict__ wqt, float* __restrict__ wkt)
{
    __shared__ float tile[64][65];
    const int bi = blockIdx.x;   // c tile
    const int bj = blockIdx.y;   // k tile
    const int t = threadIdx.x;
    const int c0 = bi * 64, k0 = bj * 64;
    const float* src = wq; float* dst = wqt;
#pragma unroll
    for (int m = 0; m < 2; ++m) {
        __syncthreads();
#pragma unroll
        for (int it = 0; it < 4; ++it) {
            int r = it * 16 + (t >> 4);
            int cc = (t & 15) * 4;
            float4 v = *(const float4*)(src + (size_t)(c0 + r) * D_ + k0 + cc);
            tile[r][cc] = v.x; tile[r][cc + 1] = v.y;
            tile[r][cc + 2] = v.z; tile[r][cc + 3] = v.w;
        }
        __syncthreads();
#pragma unroll
        for (int it = 0; it < 4; ++it) {
            int cl = t & 63;
            int kq = it * 4 + (t >> 6);          // local k-quad 0..15
            float4 v;
            v.x = tile[cl][kq * 4 + 0]; v.y = tile[cl][kq * 4 + 1];
            v.z = tile[cl][kq * 4 + 2]; v.w = tile[cl][kq * 4 + 3];
            size_t o = ((size_t)((k0 >> 2) + kq) * 512 + (c0 + cl)) * 4;
            *(float4*)(dst + o) = v;
        }
        src = wk; dst = wkt;
    }
}

__global__ void zero_fix(int* c) { if (threadIdx.x == 0 && blockIdx.x == 0) *c = 0; }

// ---------------------------------------------------------------------------
// Shared-A bf16 MFMA kernel (unchanged — verified).
// part layout: [NCT][B][L][3]
// ---------------------------------------------------------------------------
__global__ __launch_bounds__(256, 2) void qk_mfma(
    const float* __restrict__ h,
    const u16* __restrict__ wqh, const u16* __restrict__ wkh,
    float* __restrict__ part)
{
    const int ct = blockIdx.x, rt = blockIdx.y, b = blockIdx.z;
    const int t = threadIdx.x, wid = t >> 6, lane = t & 63;
    const int l15 = lane & 15, l4 = lane >> 4;

    __shared__ __align__(16) u16 ah[144 * 32];
    __shared__ float red[4][BM][3];

    if (t < 240) ((u32*)ah)[2064 + t] = 0;

    const int r0 = rt * BM;
    const float* hb = h + (size_t)b * L_ * D_;

    const float* sp0 = hb + (size_t)(r0 + (t >> 2)) * D_ + (t & 3) * 8;
    const float* sp1 = hb + (size_t)(r0 + 64 + (t >> 2)) * D_ + (t & 3) * 8;
    int r128 = r0 + BM; if (r128 > L_ - 1) r128 = L_ - 1;
    const float* sp2 = hb + (size_t)r128 * D_ + (t & 3) * 8;

    const int colb = ct * 128 + wid * 32;
    const u16* bq0 = wqh + (size_t)(colb + l15) * D_ + l4 * 8;
    const u16* bq1 = bq0 + (size_t)16 * D_;
    const u16* bk0 = wkh + (size_t)(colb + l15) * D_ + l4 * 8;
    const u16* bk1 = bk0 + (size_t)16 * D_;

    f32x4 accq[8][2], acck[8][2], ackl[2];
    const f32x4 zero = {0.f, 0.f, 0.f, 0.f};
#pragma unroll
    for (int rf = 0; rf < 8; ++rf) {
        accq[rf][0] = zero; accq[rf][1] = zero;
        acck[rf][0] = zero; acck[rf][1] = zero;
    }
    ackl[0] = zero; ackl[1] = zero;

    ushort8 c0 = ldcvt(sp0);
    ushort8 c1 = ldcvt(sp1);
    ushort8 c2 = {0,0,0,0,0,0,0,0};
    if (t < 4) c2 = ldcvt(sp2);

    for (int s = 0; s < NSTEP; ++s) {
        const int so = s * 32;
        __syncthreads();
        *(ushort8*)(&ah[t * 8]) = c0;
        *(ushort8*)(&ah[(t + 256) * 8]) = c1;
        if (t < 4) *(ushort8*)(&ah[(512 + t) * 8]) = c2;
        __syncthreads();

        bf16x8 fbq0 = *(const bf16x8*)(bq0 + so);
        bf16x8 fbq1 = *(const bf16x8*)(bq1 + so);
        bf16x8 fbk0 = *(const bf16x8*)(bk0 + so);
        bf16x8 fbk1 = *(const bf16x8*)(bk1 + so);

        const int sn = (s + 1 < NSTEP) ? (s + 1) * 32 : s * 32;
        c0 = ldcvt(sp0 + sn);
        c1 = ldcvt(sp1 + sn);
        if (t < 4) c2 = ldcvt(sp2 + sn);

#pragma unroll
        for (int rf = 0; rf < 8; ++rf) {
            bf16x8 a = *(const bf16x8*)(&ah[(rf * 16 + l15) * 32 + l4 * 8]);
            accq[rf][0] = __builtin_amdgcn_mfma_f32_16x16x32_bf16(a, fbq0, accq[rf][0], 0, 0, 0);
            accq[rf][1] = __builtin_amdgcn_mfma_f32_16x16x32_bf16(a, fbq1, accq[rf][1], 0, 0, 0);
            acck[rf][0] = __builtin_amdgcn_mfma_f32_16x16x32_bf16(a, fbk0, acck[rf][0], 0, 0, 0);
            acck[rf][1] = __builtin_amdgcn_mfma_f32_16x16x32_bf16(a, fbk1, acck[rf][1], 0, 0, 0);
        }
        bf16x8 al = *(const bf16x8*)(&ah[(128 + l15) * 32 + l4 * 8]);
        ackl[0] = __builtin_amdgcn_mfma_f32_16x16x32_bf16(al, fbk0, ackl[0], 0, 0, 0);
        ackl[1] = __builtin_amdgcn_mfma_f32_16x16x32_bf16(al, fbk1, ackl[1], 0, 0, 0);
    }

    // epilogue: per-row partials. C/D layout: col=lane&15, row=(lane>>4)*4+reg.
#pragma unroll
    for (int rf = 0; rf < 8; ++rf) {
#pragma unroll
        for (int reg = 0; reg < 4; ++reg) {
            float pq = 0.f, pk = 0.f, pd = 0.f;
#pragma unroll
            for (int cf = 0; cf < 2; ++cf) {
                float q  = accq[rf][cf][reg];
                float kv = acck[rf][cf][reg];
                pq += q * q;
                pk += kv * kv;
                float ksh;
                if (reg < 3) {
                    ksh = acck[rf][cf][reg + 1];
                } else {
                    float up = __shfl(acck[rf][cf][0], (lane + 16) & 63);
                    float nx0 = (rf < 7) ? acck[rf + 1][cf][0] : ackl[cf][0];
                    float nx = __shfl(nx0, l15);
                    ksh = (l4 == 3) ? nx : up;
                }
                pd += q * ksh;
            }
#pragma unroll
            for (int off = 1; off < 16; off <<= 1) {
                pq += __shfl_xor(pq, off);
                pk += __shfl_xor(pk, off);
                pd += __shfl_xor(pd, off);
            }
            if (l15 == 0) {
                int row = rf * 16 + l4 * 4 + reg;
                red[wid][row][0] = pq;
                red[wid][row][1] = pk;
                red[wid][row][2] = pd;
            }
        }
    }
    __syncthreads();
    if (t < BM) {
        float pq = red[0][t][0] + red[1][t][0] + red[2][t][0] + red[3][t][0];
        float pk = red[0][t][1] + red[1][t][1] + red[2][t][1] + red[3][t][1];
        float pd = red[0][t][2] + red[1][t][2] + red[2][t][2] + red[3][t][2];
        size_t o = (((size_t)ct * B_ + b) * L_ + (r0 + t)) * 3;
        part[o + 0] = pq; part[o + 1] = pk; part[o + 2] = pd;
    }
}

// ---------------------------------------------------------------------------
// reduce partials -> p (nk read shifted by one row); flag borderline rows
// ---------------------------------------------------------------------------
__global__ __launch_bounds__(256) void cos_reduce(
    const float* __restrict__ part, float* __restrict__ p,
    int* __restrict__ fix_cnt, int* __restrict__ fix_list)
{
    int idx = blockIdx.x * 256 + threadIdx.x;
    if (idx >= B_ * L_) return;
    int b = idx / L_;
    int tp = idx % L_;
    if (tp == 0) { p[idx] = 1.0f; return; }
    int l = tp - 1;
    float nq = 0.f, nk = 0.f, dt = 0.f;
#pragma unroll
    for (int ct = 0; ct < NCT; ++ct) {
        size_t o = (((size_t)ct * B_ + b) * L_ + l) * 3;
        nq += part[o + 0];
        dt += part[o + 2];
        nk += part[o + 4];        // part[...][l+1][1]
    }
    float qn = sqrtf(nq); if (qn < 1e-12f) qn = 1e-12f;
    float kn = sqrtf(nk); if (kn < 1e-12f) kn = 1e-12f;
    float cs = dt / (qn * kn);
    float pr = 0.5f * (1.0f - cs);
    pr = fminf(fmaxf(pr, 0.0f), 1.0f);
    p[idx] = pr;
    if (fabsf(cs) < FIX_TAU) {
        int slot = atomicAdd(fix_cnt, 1);
        if (slot < MAXFIX) fix_list[slot] = idx;
    }
}

// ---------------------------------------------------------------------------
// fp32 fixup: block = 256 threads, FTILE=8 borderline rows, all 512 cols.
// h rows in LDS (broadcast reads); thread t owns columns {t, t+256};
// weights read via blocked-transposed layout (coalesced float4 of 4 k).
// 32 scalar accumulators/thread -> no spill. Deterministic.
// ---------------------------------------------------------------------------
__global__ __launch_bounds__(256) void fixup_main(
    const float* __restrict__ h,
    const float* __restrict__ wqt, const float* __restrict__ wkt,
    const int* __restrict__ fix_cnt, const int* __restrict__ fix_list,
    float* __restrict__ p)
{
    __shared__ float hq[FTILE][D_];
    __shared__ float hk[FTILE][D_];
    __shared__ float red[FTILE][3][4];
    const int t = threadIdx.x, wid = t >> 6, lane = t & 63;
    int n = *fix_cnt; if (n > MAXFIX) n = MAXFIX;
    const int ntiles = (n + FTILE - 1) / FTILE;

    for (int tile = blockIdx.x; tile < ntiles; tile += gridDim.x) {
        __syncthreads();
#pragma unroll
        for (int r = 0; r < FTILE; ++r) {
            int s = tile * FTILE + r;
            int idx = fix_list[s < n ? s : 0];
            int bb = idx >> 13;                  // L_ = 8192
            int tp = idx & (L_ - 1);             // >= 1 for flagged rows
            const float* hr = h + ((size_t)bb * L_ + (tp - 1)) * D_;
            ((float2*)hq[r])[t] = ((const float2*)hr)[t];
            ((float2*)hk[r])[t] = ((const float2*)(hr + D_))[t];
        }
        __syncthreads();

        float qa0[FTILE], qa1[FTILE], ka0[FTILE], ka1[FTILE];
#pragma unroll
        for (int r = 0; r < FTILE; ++r) { qa0[r] = qa1[r] = ka0[r] = ka1[r] = 0.f; }

        for (int kq = 0; kq < D_ / 4; ++kq) {
            float4 w0 = *(const float4*)(wqt + ((size_t)kq * 512 + t) * 4);
            float4 w1 = *(const float4*)(wqt + ((size_t)kq * 512 + t + 256) * 4);
            float4 x0 = *(const float4*)(wkt + ((size_t)kq * 512 + t) * 4);
            float4 x1 = *(const float4*)(wkt + ((size_t)kq * 512 + t + 256) * 4);
#pragma unroll
            for (int r = 0; r < FTILE; ++r) {
                float4 hv = *(const float4*)(&hq[r][kq * 4]);
                float4 kv = *(const float4*)(&hk[r][kq * 4]);
                qa0[r] += hv.x * w0.x + hv.y * w0.y + hv.z * w0.z + hv.w * w0.w;
                qa1[r] += hv.x * w1.x + hv.y * w1.y + hv.z * w1.z + hv.w * w1.w;
                ka0[r] += kv.x * x0.x + kv.y * x0.y + kv.z * x0.z + kv.w * x0.w;
                ka1[r] += kv.x * x1.x + kv.y * x1.y + kv.z * x1.z + kv.w * x1.w;
            }
        }

#pragma unroll
        for (int r = 0; r < FTILE; ++r) {
            float pq = qa0[r] * qa0[r] + qa1[r] * qa1[r];
            float pk = ka0[r] * ka0[r] + ka1[r] * ka1[r];
            float pd = qa0[r] * ka0[r] + qa1[r] * ka1[r];
#pragma unroll
            for (int off = 1; off < 64; off <<= 1) {
                pq += __shfl_xor(pq, off);
                pk += __shfl_xor(pk, off);
                pd += __shfl_xor(pd, off);
            }
            if (lane == 0) { red[r][0][wid] = pq; red[r][1][wid] = pk; red[r][2][wid] = pd; }
        }
        __syncthreads();
        if (t < FTILE) {
            int s = tile * FTILE + t;
            if (s < n) {
                float nq = red[t][0][0] + red[t][0][1] + red[t][0][2] + red[t][0][3];
                float nk = red[t][1][0] + red[t][1][1] + red[t][1][2] + red[t][1][3];
                float dt = red[t][2][0] + red[t][2][1] + red[t][2][2] + red[t][2][3];
                float qn = sqrtf(nq); if (qn < 1e-12f) qn = 1e-12f;
                float kn = sqrtf(nk); if (kn < 1e-12f) kn = 1e-12f;
                float cs = dt / (qn * kn);
                float pr = 0.5f * (1.0f - cs);
                pr = fminf(fmaxf(pr, 0.0f), 1.0f);
                p[fix_list[s]] = pr;
            }
        }
    }
}

// ---------------------------------------------------------------------------
// EMA scan, float2 per thread, branchless (unchanged)
// ---------------------------------------------------------------------------
__global__ __launch_bounds__(256) void scan_a(
    const float* __restrict__ h, const float* __restrict__ p,
    float* __restrict__ Bc, float* __restrict__ Ac)
{
    const int t = threadIdx.x;
    const int c = blockIdx.x, b = blockIdx.y;
    const int l0 = c * CHUNK;
    const float* pb = p + (size_t)b * L_ + l0;
    const float2* hb = (const float2*)(h + ((size_t)b * L_ + l0) * D_) + t;

    float2 st = {0.f, 0.f};
    float ap = 1.f;
#pragma unroll 4
    for (int i = 0; i < CHUNK; ++i) {
        float pr = pb[i];
        float2 hv = hb[(size_t)i * 256];
        bool sel = pr > 0.5f;
        float a = sel ? 1.f - pr : 1.f;
        float g = sel ? pr : 0.f;
        st.x = a * st.x + g * hv.x;
        st.y = a * st.y + g * hv.y;
        ap *= a;
    }
    ((float2*)Bc)[((size_t)b * NCHUNK + c) * 256 + t] = st;
    if (t == 0) Ac[b * NCHUNK + c] = ap;
}

__global__ __launch_bounds__(256) void scan_b(
    const float* __restrict__ Ac, const float* __restrict__ Bc,
    const float* __restrict__ det, float* __restrict__ carry)
{
    const int t = threadIdx.x;
    const int b = blockIdx.x;
    float2 st = ((const float2*)det)[(size_t)b * 256 + t];
    for (int c = 0; c < NCHUNK; ++c) {
        ((float2*)carry)[((size_t)b * NCHUNK + c) * 256 + t] = st;
        float a = Ac[b * NCHUNK + c];
        float2 bc = ((const float2*)Bc)[((size_t)b * NCHUNK + c) * 256 + t];
        st.x = a * st.x + bc.x;
        st.y = a * st.y + bc.y;
    }
}

__global__ __launch_bounds__(256) void scan_c(
    const float* __restrict__ h, const float* __restrict__ p,
    const float* __restrict__ res, const float* __restrict__ carry,
    float* __restrict__ out)
{
    const int t = threadIdx.x;
    const int c = blockIdx.x, b = blockIdx.y;
    const int l0 = c * CHUNK;
    const float* pb = p + (size_t)b * L_ + l0;
    const size_t base = ((size_t)b * L_ + l0) * 256 + t;   // float2 units
    const float2* hb = (const float2*)h + base;
    const float2* rb = (const float2*)res + base;
    float2* ob = (float2*)out + base;

    float2 st = ((const float2*)carry)[((size_t)b * NCHUNK + c) * 256 + t];
#pragma unroll 4
    for (int i = 0; i < CHUNK; ++i) {
        float pr = pb[i];
        float2 hv = hb[(size_t)i * 256];
        float2 rv = rb[(size_t)i * 256];
        bool sel = pr > 0.5f;
        float a = sel ? 1.f - pr : 1.f;
        float g = sel ? pr : 0.f;
        st.x = a * st.x + g * hv.x;
        st.y = a * st.y + g * hv.y;
        float2 ov; ov.x = rv.x + st.x; ov.y = rv.y + st.y;
        ob[(size_t)i * 256] = ov;
    }
}

// ---------------------------------------------------------------------------
extern "C" void kernel_launch(void* const* d_in, const int* in_sizes, int n_in,
                              void* d_out, int out_size, void* d_ws, size_t ws_size,
                              hipStream_t stream)
{
    const float* h   = (const float*)d_in[0];
    const float* res = (const float*)d_in[1];
    const float* wq  = (const float*)d_in[2];
    const float* wk  = (const float*)d_in[3];
    const float* det = (const float*)d_in[4];
    float* out = (float*)d_out;

    // ws layout (floats)
    float* ws = (float*)d_ws;
    float* part  = ws;                                     // 393216
    float* p     = part + (size_t)NCT * B_ * L_ * 3;       // 32768
    float* Ac    = p + (size_t)B_ * L_;                    // 512
    float* Bc    = Ac + (size_t)B_ * NCHUNK;               // 262144
    float* carry = Bc + (size_t)B_ * NCHUNK * D_;          // 262144
    int*  fix_cnt  = (int*)(carry + (size_t)B_ * NCHUNK * D_);
    int*  fix_list = fix_cnt + 4;                          // MAXFIX ints
    u16* wqh = (u16*)(fix_list + MAXFIX);                  // D*D u16 each
    u16* wkh = wqh + (size_t)D_ * D_;
    float* wqt = (float*)(wkh + (size_t)D_ * D_);          // D*D f32 each
    float* wkt = wqt + (size_t)D_ * D_;

    conv_w<<<(D_ * D_ + 255) / 256, 256, 0, stream>>>(wq, wk, wqh, wkh);
    transp_w<<<dim3(8, 8), 256, 0, stream>>>(wq, wk, wqt, wkt);
    zero_fix<<<1, 64, 0, stream>>>(fix_cnt);
    qk_mfma<<<dim3(NCT, NRT, B_), 256, 0, stream>>>(h, wqh, wkh, part);
    cos_reduce<<<(B_ * L_ + 255) / 256, 256, 0, stream>>>(part, p, fix_cnt, fix_list);
    fixup_main<<<128, 256, 0, stream>>>(h, wqt, wkt, fix_cnt, fix_list, p);
    scan_a<<<dim3(NCHUNK, B_), 256, 0, stream>>>(h, p, Bc, Ac);
    scan_b<<<B_, 256, 0, stream>>>(Ac, Bc, det, carry);
    scan_c<<<dim3(NCHUNK, B_), 256, 0, stream>>>(h, p, res, carry, out);
}

// Round 6
// 212.826 us; speedup vs baseline: 1.7055x; 1.4586x over previous
//
#include <hip/hip_runtime.h>
#include <math.h>

// Problem constants
#define B_  4
#define L_  8192
#define D_  512

// MFMA GEMM tiling
#define BM   128
#define NCT  4                 // col tiles of 128
#define NRT  (L_ / BM)         // 64
#define NSTEP 16               // K = 512 / 32

// Scan chunking
#define CHUNK 64
#define NCHUNK (L_ / CHUNK)    // 128

#define MAXFIX 16380
#define FIX_TAU 1.0e-3f
#define FTILE 4                // borderline rows per fixup block

typedef short bf16x8 __attribute__((ext_vector_type(8)));
typedef float f32x4 __attribute__((ext_vector_type(4)));
typedef unsigned short u16;
typedef u16 ushort8 __attribute__((ext_vector_type(8)));
typedef unsigned int u32;

__device__ __forceinline__ u16 f2bf_rne(float f) {
    unsigned u = __float_as_uint(f);
    unsigned r = (u + 0x7FFFu + ((u >> 16) & 1u)) >> 16;
    return (u16)r;
}

__device__ __forceinline__ ushort8 cvt8(float4 a, float4 b) {
    ushort8 r;
    r[0] = f2bf_rne(a.x); r[1] = f2bf_rne(a.y);
    r[2] = f2bf_rne(a.z); r[3] = f2bf_rne(a.w);
    r[4] = f2bf_rne(b.x); r[5] = f2bf_rne(b.y);
    r[6] = f2bf_rne(b.z); r[7] = f2bf_rne(b.w);
    return r;
}

__device__ __forceinline__ ushort8 ldcvt(const float* p) {
    float4 a = *(const float4*)p;
    float4 b = *(const float4*)(p + 4);
    return cvt8(a, b);
}

// ---------------------------------------------------------------------------
// Weight conversion: fp32 -> bf16 (hi only)
// ---------------------------------------------------------------------------
__global__ __launch_bounds__(256) void conv_w(
    const float* __restrict__ wq, const float* __restrict__ wk,
    u16* __restrict__ qh, u16* __restrict__ kh)
{
    int i = blockIdx.x * 256 + threadIdx.x;
    if (i >= D_ * D_) return;
    qh[i] = f2bf_rne(wq[i]);
    kh[i] = f2bf_rne(wk[i]);
}

// ---------------------------------------------------------------------------
// Blocked-transpose fp32 weights for the fixup:
//   wt[(k>>2)*2048 + c*4 + (k&3)] = w[c][k]
// ---------------------------------------------------------------------------
__global__ __launch_bounds__(256) void transp_w(
    const float* __restrict__ wq, const float* __restrict__ wk,
    float* __restrict__ wqt, float* __restrict__ wkt)
{
    __shared__ float tile[64][65];
    const int bi = blockIdx.x;   // c tile
    const int bj = blockIdx.y;   // k tile
    const int t = threadIdx.x;
    const int c0 = bi * 64, k0 = bj * 64;
    const float* src = wq; float* dst = wqt;
#pragma unroll
    for (int m = 0; m < 2; ++m) {
        __syncthreads();
#pragma unroll
        for (int it = 0; it < 4; ++it) {
            int r = it * 16 + (t >> 4);
            int cc = (t & 15) * 4;
            float4 v = *(const float4*)(src + (size_t)(c0 + r) * D_ + k0 + cc);
            tile[r][cc] = v.x; tile[r][cc + 1] = v.y;
            tile[r][cc + 2] = v.z; tile[r][cc + 3] = v.w;
        }
        __syncthreads();
#pragma unroll
        for (int it = 0; it < 4; ++it) {
            int cl = t & 63;
            int kq = it * 4 + (t >> 6);          // local k-quad 0..15
            float4 v;
            v.x = tile[cl][kq * 4 + 0]; v.y = tile[cl][kq * 4 + 1];
            v.z = tile[cl][kq * 4 + 2]; v.w = tile[cl][kq * 4 + 3];
            size_t o = ((size_t)((k0 >> 2) + kq) * 512 + (c0 + cl)) * 4;
            *(float4*)(dst + o) = v;
        }
        src = wk; dst = wkt;
    }
}

__global__ void zero_fix(int* c) { if (threadIdx.x == 0 && blockIdx.x == 0) *c = 0; }

// ---------------------------------------------------------------------------
// Shared-A bf16 MFMA kernel (unchanged — verified).
// part layout: [NCT][B][L][3]
// ---------------------------------------------------------------------------
__global__ __launch_bounds__(256, 2) void qk_mfma(
    const float* __restrict__ h,
    const u16* __restrict__ wqh, const u16* __restrict__ wkh,
    float* __restrict__ part)
{
    const int ct = blockIdx.x, rt = blockIdx.y, b = blockIdx.z;
    const int t = threadIdx.x, wid = t >> 6, lane = t & 63;
    const int l15 = lane & 15, l4 = lane >> 4;

    __shared__ __align__(16) u16 ah[144 * 32];
    __shared__ float red[4][BM][3];

    if (t < 240) ((u32*)ah)[2064 + t] = 0;

    const int r0 = rt * BM;
    const float* hb = h + (size_t)b * L_ * D_;

    const float* sp0 = hb + (size_t)(r0 + (t >> 2)) * D_ + (t & 3) * 8;
    const float* sp1 = hb + (size_t)(r0 + 64 + (t >> 2)) * D_ + (t & 3) * 8;
    int r128 = r0 + BM; if (r128 > L_ - 1) r128 = L_ - 1;
    const float* sp2 = hb + (size_t)r128 * D_ + (t & 3) * 8;

    const int colb = ct * 128 + wid * 32;
    const u16* bq0 = wqh + (size_t)(colb + l15) * D_ + l4 * 8;
    const u16* bq1 = bq0 + (size_t)16 * D_;
    const u16* bk0 = wkh + (size_t)(colb + l15) * D_ + l4 * 8;
    const u16* bk1 = bk0 + (size_t)16 * D_;

    f32x4 accq[8][2], acck[8][2], ackl[2];
    const f32x4 zero = {0.f, 0.f, 0.f, 0.f};
#pragma unroll
    for (int rf = 0; rf < 8; ++rf) {
        accq[rf][0] = zero; accq[rf][1] = zero;
        acck[rf][0] = zero; acck[rf][1] = zero;
    }
    ackl[0] = zero; ackl[1] = zero;

    ushort8 c0 = ldcvt(sp0);
    ushort8 c1 = ldcvt(sp1);
    ushort8 c2 = {0,0,0,0,0,0,0,0};
    if (t < 4) c2 = ldcvt(sp2);

    for (int s = 0; s < NSTEP; ++s) {
        const int so = s * 32;
        __syncthreads();
        *(ushort8*)(&ah[t * 8]) = c0;
        *(ushort8*)(&ah[(t + 256) * 8]) = c1;
        if (t < 4) *(ushort8*)(&ah[(512 + t) * 8]) = c2;
        __syncthreads();

        bf16x8 fbq0 = *(const bf16x8*)(bq0 + so);
        bf16x8 fbq1 = *(const bf16x8*)(bq1 + so);
        bf16x8 fbk0 = *(const bf16x8*)(bk0 + so);
        bf16x8 fbk1 = *(const bf16x8*)(bk1 + so);

        const int sn = (s + 1 < NSTEP) ? (s + 1) * 32 : s * 32;
        c0 = ldcvt(sp0 + sn);
        c1 = ldcvt(sp1 + sn);
        if (t < 4) c2 = ldcvt(sp2 + sn);

#pragma unroll
        for (int rf = 0; rf < 8; ++rf) {
            bf16x8 a = *(const bf16x8*)(&ah[(rf * 16 + l15) * 32 + l4 * 8]);
            accq[rf][0] = __builtin_amdgcn_mfma_f32_16x16x32_bf16(a, fbq0, accq[rf][0], 0, 0, 0);
            accq[rf][1] = __builtin_amdgcn_mfma_f32_16x16x32_bf16(a, fbq1, accq[rf][1], 0, 0, 0);
            acck[rf][0] = __builtin_amdgcn_mfma_f32_16x16x32_bf16(a, fbk0, acck[rf][0], 0, 0, 0);
            acck[rf][1] = __builtin_amdgcn_mfma_f32_16x16x32_bf16(a, fbk1, acck[rf][1], 0, 0, 0);
        }
        bf16x8 al = *(const bf16x8*)(&ah[(128 + l15) * 32 + l4 * 8]);
        ackl[0] = __builtin_amdgcn_mfma_f32_16x16x32_bf16(al, fbk0, ackl[0], 0, 0, 0);
        ackl[1] = __builtin_amdgcn_mfma_f32_16x16x32_bf16(al, fbk1, ackl[1], 0, 0, 0);
    }

    // epilogue: per-row partials. C/D layout: col=lane&15, row=(lane>>4)*4+reg.
#pragma unroll
    for (int rf = 0; rf < 8; ++rf) {
#pragma unroll
        for (int reg = 0; reg < 4; ++reg) {
            float pq = 0.f, pk = 0.f, pd = 0.f;
#pragma unroll
            for (int cf = 0; cf < 2; ++cf) {
                float q  = accq[rf][cf][reg];
                float kv = acck[rf][cf][reg];
                pq += q * q;
                pk += kv * kv;
                float ksh;
                if (reg < 3) {
                    ksh = acck[rf][cf][reg + 1];
                } else {
                    float up = __shfl(acck[rf][cf][0], (lane + 16) & 63);
                    float nx0 = (rf < 7) ? acck[rf + 1][cf][0] : ackl[cf][0];
                    float nx = __shfl(nx0, l15);
                    ksh = (l4 == 3) ? nx : up;
                }
                pd += q * ksh;
            }
#pragma unroll
            for (int off = 1; off < 16; off <<= 1) {
                pq += __shfl_xor(pq, off);
                pk += __shfl_xor(pk, off);
                pd += __shfl_xor(pd, off);
            }
            if (l15 == 0) {
                int row = rf * 16 + l4 * 4 + reg;
                red[wid][row][0] = pq;
                red[wid][row][1] = pk;
                red[wid][row][2] = pd;
            }
        }
    }
    __syncthreads();
    if (t < BM) {
        float pq = red[0][t][0] + red[1][t][0] + red[2][t][0] + red[3][t][0];
        float pk = red[0][t][1] + red[1][t][1] + red[2][t][1] + red[3][t][1];
        float pd = red[0][t][2] + red[1][t][2] + red[2][t][2] + red[3][t][2];
        size_t o = (((size_t)ct * B_ + b) * L_ + (r0 + t)) * 3;
        part[o + 0] = pq; part[o + 1] = pk; part[o + 2] = pd;
    }
}

// ---------------------------------------------------------------------------
// reduce partials -> p (nk read shifted by one row); flag borderline rows
// ---------------------------------------------------------------------------
__global__ __launch_bounds__(256) void cos_reduce(
    const float* __restrict__ part, float* __restrict__ p,
    int* __restrict__ fix_cnt, int* __restrict__ fix_list)
{
    int idx = blockIdx.x * 256 + threadIdx.x;
    if (idx >= B_ * L_) return;
    int b = idx / L_;
    int tp = idx % L_;
    if (tp == 0) { p[idx] = 1.0f; return; }
    int l = tp - 1;
    float nq = 0.f, nk = 0.f, dt = 0.f;
#pragma unroll
    for (int ct = 0; ct < NCT; ++ct) {
        size_t o = (((size_t)ct * B_ + b) * L_ + l) * 3;
        nq += part[o + 0];
        dt += part[o + 2];
        nk += part[o + 4];        // part[...][l+1][1]
    }
    float qn = sqrtf(nq); if (qn < 1e-12f) qn = 1e-12f;
    float kn = sqrtf(nk); if (kn < 1e-12f) kn = 1e-12f;
    float cs = dt / (qn * kn);
    float pr = 0.5f * (1.0f - cs);
    pr = fminf(fmaxf(pr, 0.0f), 1.0f);
    p[idx] = pr;
    if (fabsf(cs) < FIX_TAU) {
        int slot = atomicAdd(fix_cnt, 1);
        if (slot < MAXFIX) fix_list[slot] = idx;
    }
}

// ---------------------------------------------------------------------------
// fp32 fixup: block = 256 threads, FTILE=4 borderline rows, all 512 cols.
// Weight stream software-pipelined: next iteration's 4 float4 loads issued
// before current iteration's FMAs (rotation registers, unroll 4).
// ---------------------------------------------------------------------------
__global__ __launch_bounds__(256) void fixup_main(
    const float* __restrict__ h,
    const float* __restrict__ wqt, const float* __restrict__ wkt,
    const int* __restrict__ fix_cnt, const int* __restrict__ fix_list,
    float* __restrict__ p)
{
    __shared__ float hq[FTILE][D_];
    __shared__ float hk[FTILE][D_];
    __shared__ float red[FTILE][3][4];
    const int t = threadIdx.x, wid = t >> 6, lane = t & 63;
    int n = *fix_cnt; if (n > MAXFIX) n = MAXFIX;
    const int ntiles = (n + FTILE - 1) / FTILE;

    for (int tile = blockIdx.x; tile < ntiles; tile += gridDim.x) {
        __syncthreads();
#pragma unroll
        for (int r = 0; r < FTILE; ++r) {
            int s = tile * FTILE + r;
            int idx = fix_list[s < n ? s : 0];
            int bb = idx >> 13;                  // L_ = 8192
            int tp = idx & (L_ - 1);             // >= 1 for flagged rows
            const float* hr = h + ((size_t)bb * L_ + (tp - 1)) * D_;
            ((float2*)hq[r])[t] = ((const float2*)hr)[t];
            ((float2*)hk[r])[t] = ((const float2*)(hr + D_))[t];
        }
        __syncthreads();

        float qa0[FTILE], qa1[FTILE], ka0[FTILE], ka1[FTILE];
#pragma unroll
        for (int r = 0; r < FTILE; ++r) { qa0[r] = qa1[r] = ka0[r] = ka1[r] = 0.f; }

        // software-pipelined weight stream
        float4 wc0 = *(const float4*)(wqt + ((size_t)0 * 512 + t) * 4);
        float4 wc1 = *(const float4*)(wqt + ((size_t)0 * 512 + t + 256) * 4);
        float4 xc0 = *(const float4*)(wkt + ((size_t)0 * 512 + t) * 4);
        float4 xc1 = *(const float4*)(wkt + ((size_t)0 * 512 + t + 256) * 4);
#pragma unroll 4
        for (int kq = 0; kq < D_ / 4; ++kq) {
            const int kn = (kq + 1) & (D_ / 4 - 1);   // wraps on last iter (harmless)
            float4 wn0 = *(const float4*)(wqt + ((size_t)kn * 512 + t) * 4);
            float4 wn1 = *(const float4*)(wqt + ((size_t)kn * 512 + t + 256) * 4);
            float4 xn0 = *(const float4*)(wkt + ((size_t)kn * 512 + t) * 4);
            float4 xn1 = *(const float4*)(wkt + ((size_t)kn * 512 + t + 256) * 4);
#pragma unroll
            for (int r = 0; r < FTILE; ++r) {
                float4 hv = *(const float4*)(&hq[r][kq * 4]);
                float4 kv = *(const float4*)(&hk[r][kq * 4]);
                qa0[r] += hv.x * wc0.x + hv.y * wc0.y + hv.z * wc0.z + hv.w * wc0.w;
                qa1[r] += hv.x * wc1.x + hv.y * wc1.y + hv.z * wc1.z + hv.w * wc1.w;
                ka0[r] += kv.x * xc0.x + kv.y * xc0.y + kv.z * xc0.z + kv.w * xc0.w;
                ka1[r] += kv.x * xc1.x + kv.y * xc1.y + kv.z * xc1.z + kv.w * xc1.w;
            }
            wc0 = wn0; wc1 = wn1; xc0 = xn0; xc1 = xn1;
        }

#pragma unroll
        for (int r = 0; r < FTILE; ++r) {
            float pq = qa0[r] * qa0[r] + qa1[r] * qa1[r];
            float pk = ka0[r] * ka0[r] + ka1[r] * ka1[r];
            float pd = qa0[r] * ka0[r] + qa1[r] * ka1[r];
#pragma unroll
            for (int off = 1; off < 64; off <<= 1) {
                pq += __shfl_xor(pq, off);
                pk += __shfl_xor(pk, off);
                pd += __shfl_xor(pd, off);
            }
            if (lane == 0) { red[r][0][wid] = pq; red[r][1][wid] = pk; red[r][2][wid] = pd; }
        }
        __syncthreads();
        if (t < FTILE) {
            int s = tile * FTILE + t;
            if (s < n) {
                float nq = red[t][0][0] + red[t][0][1] + red[t][0][2] + red[t][0][3];
                float nk = red[t][1][0] + red[t][1][1] + red[t][1][2] + red[t][1][3];
                float dt = red[t][2][0] + red[t][2][1] + red[t][2][2] + red[t][2][3];
                float qn = sqrtf(nq); if (qn < 1e-12f) qn = 1e-12f;
                float kn = sqrtf(nk); if (kn < 1e-12f) kn = 1e-12f;
                float cs = dt / (qn * kn);
                float pr = 0.5f * (1.0f - cs);
                pr = fminf(fmaxf(pr, 0.0f), 1.0f);
                p[fix_list[s]] = pr;
            }
        }
    }
}

// ---------------------------------------------------------------------------
// EMA scan, float2 per thread, branchless (unchanged)
// ---------------------------------------------------------------------------
__global__ __launch_bounds__(256) void scan_a(
    const float* __restrict__ h, const float* __restrict__ p,
    float* __restrict__ Bc, float* __restrict__ Ac)
{
    const int t = threadIdx.x;
    const int c = blockIdx.x, b = blockIdx.y;
    const int l0 = c * CHUNK;
    const float* pb = p + (size_t)b * L_ + l0;
    const float2* hb = (const float2*)(h + ((size_t)b * L_ + l0) * D_) + t;

    float2 st = {0.f, 0.f};
    float ap = 1.f;
#pragma unroll 4
    for (int i = 0; i < CHUNK; ++i) {
        float pr = pb[i];
        float2 hv = hb[(size_t)i * 256];
        bool sel = pr > 0.5f;
        float a = sel ? 1.f - pr : 1.f;
        float g = sel ? pr : 0.f;
        st.x = a * st.x + g * hv.x;
        st.y = a * st.y + g * hv.y;
        ap *= a;
    }
    ((float2*)Bc)[((size_t)b * NCHUNK + c) * 256 + t] = st;
    if (t == 0) Ac[b * NCHUNK + c] = ap;
}

__global__ __launch_bounds__(256) void scan_b(
    const float* __restrict__ Ac, const float* __restrict__ Bc,
    const float* __restrict__ det, float* __restrict__ carry)
{
    const int t = threadIdx.x;
    const int b = blockIdx.x;
    float2 st = ((const float2*)det)[(size_t)b * 256 + t];
    for (int c = 0; c < NCHUNK; ++c) {
        ((float2*)carry)[((size_t)b * NCHUNK + c) * 256 + t] = st;
        float a = Ac[b * NCHUNK + c];
        float2 bc = ((const float2*)Bc)[((size_t)b * NCHUNK + c) * 256 + t];
        st.x = a * st.x + bc.x;
        st.y = a * st.y + bc.y;
    }
}

__global__ __launch_bounds__(256) void scan_c(
    const float* __restrict__ h, const float* __restrict__ p,
    const float* __restrict__ res, const float* __restrict__ carry,
    float* __restrict__ out)
{
    const int t = threadIdx.x;
    const int c = blockIdx.x, b = blockIdx.y;
    const int l0 = c * CHUNK;
    const float* pb = p + (size_t)b * L_ + l0;
    const size_t base = ((size_t)b * L_ + l0) * 256 + t;   // float2 units
    const float2* hb = (const float2*)h + base;
    const float2* rb = (const float2*)res + base;
    float2* ob = (float2*)out + base;

    float2 st = ((const float2*)carry)[((size_t)b * NCHUNK + c) * 256 + t];
#pragma unroll 4
    for (int i = 0; i < CHUNK; ++i) {
        float pr = pb[i];
        float2 hv = hb[(size_t)i * 256];
        float2 rv = rb[(size_t)i * 256];
        bool sel = pr > 0.5f;
        float a = sel ? 1.f - pr : 1.f;
        float g = sel ? pr : 0.f;
        st.x = a * st.x + g * hv.x;
        st.y = a * st.y + g * hv.y;
        float2 ov; ov.x = rv.x + st.x; ov.y = rv.y + st.y;
        ob[(size_t)i * 256] = ov;
    }
}

// ---------------------------------------------------------------------------
extern "C" void kernel_launch(void* const* d_in, const int* in_sizes, int n_in,
                              void* d_out, int out_size, void* d_ws, size_t ws_size,
                              hipStream_t stream)
{
    const float* h   = (const float*)d_in[0];
    const float* res = (const float*)d_in[1];
    const float* wq  = (const float*)d_in[2];
    const float* wk  = (const float*)d_in[3];
    const float* det = (const float*)d_in[4];
    float* out = (float*)d_out;

    // ws layout (floats)
    float* ws = (float*)d_ws;
    float* part  = ws;                                     // 393216
    float* p     = part + (size_t)NCT * B_ * L_ * 3;       // 32768
    float* Ac    = p + (size_t)B_ * L_;                    // 512
    float* Bc    = Ac + (size_t)B_ * NCHUNK;               // 262144
    float* carry = Bc + (size_t)B_ * NCHUNK * D_;          // 262144
    int*  fix_cnt  = (int*)(carry + (size_t)B_ * NCHUNK * D_);
    int*  fix_list = fix_cnt + 4;                          // MAXFIX ints
    u16* wqh = (u16*)(fix_list + MAXFIX);                  // D*D u16 each
    u16* wkh = wqh + (size_t)D_ * D_;
    float* wqt = (float*)(wkh + (size_t)D_ * D_);          // D*D f32 each
    float* wkt = wqt + (size_t)D_ * D_;

    conv_w<<<(D_ * D_ + 255) / 256, 256, 0, stream>>>(wq, wk, wqh, wkh);
    transp_w<<<dim3(8, 8), 256, 0, stream>>>(wq, wk, wqt, wkt);
    zero_fix<<<1, 64, 0, stream>>>(fix_cnt);
    qk_mfma<<<dim3(NCT, NRT, B_), 256, 0, stream>>>(h, wqh, wkh, part);
    cos_reduce<<<(B_ * L_ + 255) / 256, 256, 0, stream>>>(part, p, fix_cnt, fix_list);
    fixup_main<<<256, 256, 0, stream>>>(h, wqt, wkt, fix_cnt, fix_list, p);
    scan_a<<<dim3(NCHUNK, B_), 256, 0, stream>>>(h, p, Bc, Ac);
    scan_b<<<B_, 256, 0, stream>>>(Ac, Bc, det, carry);
    scan_c<<<dim3(NCHUNK, B_), 256, 0, stream>>>(h, p, res, carry, out);
}